// Round 4
// baseline (27.941 us; speedup 1.0000x reference)
//
#include <hip/hip_runtime.h>

constexpr int HS = 360, WS = 640, NPIX = HS * WS;
constexpr int NSQ = 8, NSAMP = 10, NPT = NSAMP + 2;
constexpr float FARV = 1.5f, EPSV = 1e-6f;
constexpr float SHARPV = 1000.0f, TAUV = 100.0f;

__global__ __launch_bounds__(256) void fill_kernel(float* __restrict__ out) {
  const int i = blockIdx.x * blockDim.x + threadIdx.x;
  if (i < NPIX) out[i] = FARV;
}

// one thread = one (pixel, superquadric) pair; combine with atomicMin on
// float bits (all depths >= 0, so int ordering == float ordering)
__global__ __launch_bounds__(256) void depth_kernel(
    const float* __restrict__ poses, const float* __restrict__ params,
    const float* __restrict__ rays_d, const float* __restrict__ rays_o,
    const float* __restrict__ tt, int* __restrict__ out)
{
  const int pix = blockIdx.x * blockDim.x + threadIdx.x;
  const int n = blockIdx.y;
  if (pix >= NPIX) return;

  // uniform (per-block) SQ constants -> scalar loads/ALU
  const float* P = poses + n * 16;
  const float* par = params + n * 5;
  const float R00 = P[0], R01 = P[1], R02 = P[2], p0 = P[3];
  const float R10 = P[4], R11 = P[5], R12 = P[6], p1 = P[7];
  const float R20 = P[8], R21 = P[9], R22 = P[10], p2 = P[11];
  const float is0 = 1.0f / par[0], is1 = 1.0f / par[1], is2 = 1.0f / par[2];
  const float e1 = par[3], e2 = par[4];
  const float c2 = 2.0f / e2, c21 = e2 / e1, c1 = 2.0f / e1;
  const float Kq = SHARPV * e1;   // occ = rcp(1 + exp(Kq * ln f))

  const float d0 = rays_o[0] - p0, d1 = rays_o[1] - p1, d2 = rays_o[2] - p2;
  const float tc0 = (R00 * d0 + R10 * d1 + R20 * d2) * is0;
  const float tc1 = (R01 * d0 + R11 * d1 + R21 * d2) * is1;
  const float tc2 = (R02 * d0 + R12 * d1 + R22 * d2) * is2;

  const float rd0 = rays_d[pix * 3 + 0];
  const float rd1 = rays_d[pix * 3 + 1];
  const float rd2 = rays_d[pix * 3 + 2];
  // w = (R^T rd) / sizes ; world point along ray: o + beta*rd, local q = tc + beta*w
  const float w0 = (R00 * rd0 + R10 * rd1 + R20 * rd2) * is0;
  const float w1 = (R01 * rd0 + R11 * rd1 + R21 * rd2) * is1;
  const float w2 = (R02 * rd0 + R12 * rd1 + R22 * rd2) * is2;

  const float lam2 = w0 * w0 + w1 * w1 + w2 * w2;
  const float dd = tc0 * w0 + tc1 * w1 + tc2 * w2;
  const float pb = fabsf(dd) / lam2;                 // projection foot in beta
  const float ce0 = tc0 + pb * w0;
  const float ce1 = tc1 + pb * w1;
  const float ce2 = tc2 + pb * w2;
  const float dist2 = ce0 * ce0 + ce1 * ce1 + ce2 * ce2;
  if (!(dist2 < 3.0f)) return;                       // mask: dist < sqrt(3)

  // half chord length in beta units: sqrt(3-dist2)/lam
  const float hb = sqrtf(fmaxf(3.0f - dist2, 1e-12f)) * rsqrtf(lam2);

  float beta[NPT];
  beta[0] = 0.0f;
#pragma unroll
  for (int s = 0; s < NSAMP; s++) beta[s + 1] = pb + hb * tt[s];
  beta[NPT - 1] = FARV;

  // occ for all 12 points (independent -> ILP over trans pipe)
  float occ[NPT];
#pragma unroll
  for (int k = 0; k < NPT; k++) {
    const float b = beta[k];
    const float X0 = fabsf(tc0 + b * w0) + EPSV;
    const float X1 = fabsf(tc1 + b * w1) + EPSV;
    const float X2 = fabsf(tc2 + b * w2) + EPSV;
    const float A = __expf(c2 * __logf(X0));
    const float B = __expf(c2 * __logf(X1));
    const float C = __expf(c1 * __logf(X2));
    const float g = __expf(c21 * __logf(A + B));
    const float f = g + C;
    // occ = sigmoid(SHARP*(1-F)), F=f^e1; use 1-F ~= -ln F (exact where not saturated)
    occ[k] = __builtin_amdgcn_rcpf(1.0f + __expf(Kq * __logf(f)));
  }

  float csum = 0.0f, vp = 0.0f, depth = 0.0f;
#pragma unroll
  for (int k = 0; k < NPT; k++) {
    csum += occ[k];
    const float vis = __expf(-TAUV * csum);
    if (k) depth += 0.5f * (vp + vis) * fabsf(beta[k] - beta[k - 1]);
    vp = vis;
  }

  atomicMin(out + pix, __float_as_int(depth));
}

extern "C" void kernel_launch(void* const* d_in, const int* in_sizes, int n_in,
                              void* d_out, int out_size, void* d_ws, size_t ws_size,
                              hipStream_t stream) {
  const float* poses  = (const float*)d_in[0];
  const float* params = (const float*)d_in[1];
  const float* rays_d = (const float*)d_in[2];
  const float* rays_o = (const float*)d_in[3];
  const float* t      = (const float*)d_in[4];

  const int block = 256;
  const int gridx = (NPIX + block - 1) / block;   // 900

  fill_kernel<<<gridx, block, 0, stream>>>((float*)d_out);
  depth_kernel<<<dim3(gridx, NSQ), block, 0, stream>>>(
      poses, params, rays_d, rays_o, t, (int*)d_out);
}

// Round 5
// 18.998 us; speedup vs baseline: 1.4708x; 1.4708x over previous
//
#include <hip/hip_runtime.h>

constexpr int NPIX = 360 * 640;
constexpr int NSQ = 8, NSAMP = 10, NPT = NSAMP + 2;
constexpr float FARV = 1.5f;
constexpr float SHARPV = 1000.0f;
constexpr float TAU2 = 100.0f * 1.44269504f;   // TAU * log2(e)
constexpr float DT9 = 2.0f / 9.0f;             // linspace(-1,1,10) spacing

__global__ __launch_bounds__(256) void fill_kernel(float* __restrict__ out) {
  const int i = blockIdx.x * blockDim.x + threadIdx.x;
  if (i < NPIX) out[i] = FARV;
}

// one thread = one (pixel, superquadric); combine via atomicMin on float bits
__global__ __launch_bounds__(256) void depth_kernel(
    const float* __restrict__ poses, const float* __restrict__ params,
    const float* __restrict__ rays_d, const float* __restrict__ rays_o,
    int* __restrict__ out)
{
  const int pix = blockIdx.x * blockDim.x + threadIdx.x;
  const int n = blockIdx.y;
  if (pix >= NPIX) return;

  // uniform per-block SQ constants
  const float* P = poses + n * 16;
  const float* par = params + n * 5;
  const float R00 = P[0], R01 = P[1], R02 = P[2], p0 = P[3];
  const float R10 = P[4], R11 = P[5], R12 = P[6], p1 = P[7];
  const float R20 = P[8], R21 = P[9], R22 = P[10], p2 = P[11];
  const float is0 = 1.0f / par[0], is1 = 1.0f / par[1], is2 = 1.0f / par[2];
  const float e1 = par[3], e2 = par[4];
  const float ie1 = 1.0f / e1, ie2 = 1.0f / e2;
  const float c21 = e2 * ie1;          // e2/e1
  const float Kq = SHARPV * e1;        // occ = rcp(1 + exp2(Kq*log2 f)) since F=f^e1

  // circumscribed-radius^2 bound of the F=1 surface (F homogeneous deg 2):
  // U = max(1,2^(1-e1)) * max(1,2^(1-e2));  cull if dist2 > 1.05*U  (occ <= e^-50)
  const float U = fmaxf(1.0f, __builtin_amdgcn_exp2f(1.0f - e1)) *
                  fmaxf(1.0f, __builtin_amdgcn_exp2f(1.0f - e2));
  const float thr = 1.05f * U;

  const float d0 = rays_o[0] - p0, d1 = rays_o[1] - p1, d2 = rays_o[2] - p2;
  const float tc0 = (R00 * d0 + R10 * d1 + R20 * d2) * is0;
  const float tc1 = (R01 * d0 + R11 * d1 + R21 * d2) * is1;
  const float tc2 = (R02 * d0 + R12 * d1 + R22 * d2) * is2;

  const float rd0 = rays_d[pix * 3 + 0];
  const float rd1 = rays_d[pix * 3 + 1];
  const float rd2 = rays_d[pix * 3 + 2];
  // local q(beta) = tc + beta*w ; world point = o + beta*rd so world dt == |dbeta|
  const float w0 = (R00 * rd0 + R10 * rd1 + R20 * rd2) * is0;
  const float w1 = (R01 * rd0 + R11 * rd1 + R21 * rd2) * is1;
  const float w2 = (R02 * rd0 + R12 * rd1 + R22 * rd2) * is2;

  const float lam2 = w0 * w0 + w1 * w1 + w2 * w2;
  const float dd = tc0 * w0 + tc1 * w1 + tc2 * w2;
  const float pb = fabsf(dd) * __builtin_amdgcn_rcpf(lam2);  // projection foot (beta)
  const float ce0 = fmaf(pb, w0, tc0);
  const float ce1 = fmaf(pb, w1, tc1);
  const float ce2 = fmaf(pb, w2, tc2);
  const float dist2 = ce0 * ce0 + ce1 * ce1 + ce2 * ce2;
  if (!(dist2 < thr)) return;          // tight cull (ref mask is dist2 < 3)

  // half chord of the sqrt(3) sphere, in beta units (matches ref sampling)
  const float hb = sqrtf(fmaxf(3.0f - dist2, 1e-12f)) * rsqrtf(lam2);

  float beta[NPT];
  beta[0] = 0.0f;
#pragma unroll
  for (int s = 0; s < NSAMP; s++)
    beta[s + 1] = fmaf(fmaf((float)s, DT9, -1.0f), hb, pb);
  beta[NPT - 1] = FARV;

  // occ for all 12 points (independent -> ILP on the trans pipe)
  float occ[NPT];
#pragma unroll
  for (int k = 0; k < NPT; k++) {
    const float b = beta[k];
    const float q0 = fmaf(b, w0, tc0);
    const float q1 = fmaf(b, w1, tc1);
    const float q2 = fmaf(b, w2, tc2);
    const float y0 = fmaf(q0, q0, 1e-12f);   // (|x|+1e-6)^2 ~ x^2+1e-12
    const float y1 = fmaf(q1, q1, 1e-12f);
    const float y2 = fmaf(q2, q2, 1e-12f);
    const float A = __builtin_amdgcn_exp2f(ie2 * __builtin_amdgcn_logf(y0));
    const float B = __builtin_amdgcn_exp2f(ie2 * __builtin_amdgcn_logf(y1));
    const float C = __builtin_amdgcn_exp2f(ie1 * __builtin_amdgcn_logf(y2));
    const float g = __builtin_amdgcn_exp2f(c21 * __builtin_amdgcn_logf(A + B));
    const float f = g + C;
    occ[k] = __builtin_amdgcn_rcpf(
        1.0f + __builtin_amdgcn_exp2f(Kq * __builtin_amdgcn_logf(f)));
  }

  // prefix sum (cheap serial adds) then independent exps
  float vis[NPT];
  float csum = 0.0f;
#pragma unroll
  for (int k = 0; k < NPT; k++) {
    csum += occ[k];
    vis[k] = __builtin_amdgcn_exp2f(-TAU2 * csum);
  }

  // trapezoid: interior spacing is uniform (hb*2/9)
  float mid = 0.0f;
#pragma unroll
  for (int k = 2; k <= NSAMP; k++) mid += vis[k - 1] + vis[k];
  float depth = (vis[0] + vis[1]) * fabsf(beta[1])
              + mid * (hb * DT9)
              + (vis[NPT - 2] + vis[NPT - 1]) * fabsf(FARV - beta[NPT - 2]);
  depth *= 0.5f;

  atomicMin(out + pix, __float_as_int(depth));
}

extern "C" void kernel_launch(void* const* d_in, const int* in_sizes, int n_in,
                              void* d_out, int out_size, void* d_ws, size_t ws_size,
                              hipStream_t stream) {
  const float* poses  = (const float*)d_in[0];
  const float* params = (const float*)d_in[1];
  const float* rays_d = (const float*)d_in[2];
  const float* rays_o = (const float*)d_in[3];

  const int block = 256;
  const int gridx = (NPIX + block - 1) / block;   // 900

  fill_kernel<<<gridx, block, 0, stream>>>((float*)d_out);
  depth_kernel<<<dim3(gridx, NSQ), block, 0, stream>>>(
      poses, params, rays_d, rays_o, (int*)d_out);
}

// Round 6
// 16.795 us; speedup vs baseline: 1.6636x; 1.1311x over previous
//
#include <hip/hip_runtime.h>

constexpr int NPIX = 360 * 640;            // 230400 = 900 * 256 exactly
constexpr int NSQ = 8, NSAMP = 10;
constexpr float FARV = 1.5f;
constexpr float SHARPV = 1000.0f;
constexpr float TAU2 = 100.0f * 1.44269504f;   // TAU * log2(e)
constexpr float DT9 = 2.0f / 9.0f;
constexpr int TSTRIDE = 24;                // floats per SQ in the table

// log2 of f = (y0^(1/e2)+y1^(1/e2))^(e2/e1) + y2^(1/e1), y = q^2 + 1e-12
// (v_log_f32 / v_exp_f32 are base-2)
__device__ __forceinline__ float lf_eval(float q0, float q1, float q2,
                                         float ie1, float ie2, float c21) {
  const float y0 = fmaf(q0, q0, 1e-12f);
  const float y1 = fmaf(q1, q1, 1e-12f);
  const float y2 = fmaf(q2, q2, 1e-12f);
  const float la = ie2 * __builtin_amdgcn_logf(y0);
  const float lb = ie2 * __builtin_amdgcn_logf(y1);
  const float lc = ie1 * __builtin_amdgcn_logf(y2);
  const float mab = fmaxf(la, lb), nab = fminf(la, lb);
  const float lab = mab + __builtin_amdgcn_logf(1.0f + __builtin_amdgcn_exp2f(nab - mab));
  const float lg = c21 * lab;
  const float mf = fmaxf(lg, lc), nf = fminf(lg, lc);
  return mf + __builtin_amdgcn_logf(1.0f + __builtin_amdgcn_exp2f(nf - mf));
}

// fill out with FAR; block 0 additionally builds the per-SQ constant table
__global__ __launch_bounds__(256) void fill_kernel(
    float* __restrict__ out, const float* __restrict__ poses,
    const float* __restrict__ params, const float* __restrict__ rays_o,
    float* __restrict__ tab)
{
  const int i = blockIdx.x * blockDim.x + threadIdx.x;
  out[i] = FARV;
  if (blockIdx.x == 0 && threadIdx.x < NSQ) {
    const int n = threadIdx.x;
    const float* P = poses + n * 16;
    const float* par = params + n * 5;
    const float is0 = 1.0f / par[0], is1 = 1.0f / par[1], is2 = 1.0f / par[2];
    const float e1 = par[3], e2 = par[4];
    const float ie1 = 1.0f / e1, ie2 = 1.0f / e2, c21 = e2 * ie1;
    const float Kq = SHARPV * e1;
    float* T = tab + n * TSTRIDE;
    // A = R * diag(1/s) folded: w_j = sum_i R_ij rd_i * is_j
    T[0] = P[0] * is0;  T[1] = P[1] * is1;  T[2] = P[2]  * is2;
    T[3] = P[4] * is0;  T[4] = P[5] * is1;  T[5] = P[6]  * is2;
    T[6] = P[8] * is0;  T[7] = P[9] * is1;  T[8] = P[10] * is2;
    const float d0 = rays_o[0] - P[3], d1 = rays_o[1] - P[7], d2 = rays_o[2] - P[11];
    const float tc0 = T[0] * d0 + T[3] * d1 + T[6] * d2;
    const float tc1 = T[1] * d0 + T[4] * d1 + T[7] * d2;
    const float tc2 = T[2] * d0 + T[5] * d1 + T[8] * d2;
    T[9] = tc0; T[10] = tc1; T[11] = tc2;
    T[12] = ie1; T[13] = ie2; T[14] = c21; T[15] = Kq;
    // exact circumscribed radius^2 of the F=1 surface (scaled frame)
    const float c = __builtin_amdgcn_exp2f(1.0f - e2);
    const float V1 = (e1 < 1.0f) ? __builtin_amdgcn_exp2f(1.0f - e1) : 1.0f;
    float V2;
    if (e1 < 0.999f) {
      const float cp = __builtin_amdgcn_exp2f((1.0f - e2) / (1.0f - e1));
      V2 = __builtin_amdgcn_exp2f((1.0f - e1) * __builtin_amdgcn_logf(1.0f + cp));
    } else {
      V2 = fmaxf(c, 1.0f);
    }
    T[16] = 1.02f * fmaxf(V1, V2);           // cull threshold (output-exact)
    // near point (beta=0): local coord == tc, pixel-independent
    const float lf0 = lf_eval(tc0, tc1, tc2, ie1, ie2, c21);
    const float occ0 = __builtin_amdgcn_rcpf(1.0f + __builtin_amdgcn_exp2f(Kq * lf0));
    T[17] = __builtin_amdgcn_exp2f(-TAU2 * occ0);   // vis at near point
  }
}

// one thread = one (pixel, SQ); combine via atomicMin on float bits (depth>=0)
__global__ __launch_bounds__(256) void depth_kernel(
    const float* __restrict__ rays_d, const float* __restrict__ tab,
    int* __restrict__ out)
{
  const int pix = blockIdx.x * blockDim.x + threadIdx.x;
  const float* T = tab + blockIdx.y * TSTRIDE;   // uniform -> scalar loads
  const float A00 = T[0], A01 = T[1], A02 = T[2];
  const float A10 = T[3], A11 = T[4], A12 = T[5];
  const float A20 = T[6], A21 = T[7], A22 = T[8];
  const float tc0 = T[9], tc1 = T[10], tc2 = T[11];
  const float ie1 = T[12], ie2 = T[13], c21 = T[14];
  const float Kq = T[15], thr = T[16], vis0 = T[17];

  const float rd0 = rays_d[pix * 3 + 0];
  const float rd1 = rays_d[pix * 3 + 1];
  const float rd2 = rays_d[pix * 3 + 2];
  const float w0 = A00 * rd0 + A10 * rd1 + A20 * rd2;
  const float w1 = A01 * rd0 + A11 * rd1 + A21 * rd2;
  const float w2 = A02 * rd0 + A12 * rd1 + A22 * rd2;

  const float lam2 = w0 * w0 + w1 * w1 + w2 * w2;
  const float dd = tc0 * w0 + tc1 * w1 + tc2 * w2;
  const float pb = fabsf(dd) * __builtin_amdgcn_rcpf(lam2);  // closest approach (beta)
  const float ce0 = fmaf(pb, w0, tc0);
  const float ce1 = fmaf(pb, w1, tc1);
  const float ce2 = fmaf(pb, w2, tc2);
  const float dist2 = ce0 * ce0 + ce1 * ce1 + ce2 * ce2;
  if (!(dist2 < thr)) return;

  // half chord of the sqrt(3) sphere in beta units (matches ref sampling)
  const float hb = sqrtf(fmaxf(3.0f - dist2, 1e-12f)) * rsqrtf(lam2);

  float ev[NSAMP + 1];
#pragma unroll
  for (int k = 0; k <= NSAMP; k++) {
    const float b = (k < NSAMP) ? fmaf(fmaf((float)k, DT9, -1.0f), hb, pb) : FARV;
    const float lf = lf_eval(fmaf(b, w0, tc0), fmaf(b, w1, tc1), fmaf(b, w2, tc2),
                             ie1, ie2, c21);
    const float occ = __builtin_amdgcn_rcpf(1.0f + __builtin_amdgcn_exp2f(Kq * lf));
    ev[k] = __builtin_amdgcn_exp2f(-TAU2 * occ);
  }

  float v = vis0;
  float vn = v * ev[0];
  float depth = (v + vn) * fabsf(pb - hb);       // near segment
  v = vn;
  float mid = 0.0f;
#pragma unroll
  for (int k = 1; k < NSAMP; k++) { vn = v * ev[k]; mid += v + vn; v = vn; }
  depth += mid * (hb * DT9);                      // uniform interior spacing
  vn = v * ev[NSAMP];
  depth += (v + vn) * fabsf(FARV - pb - hb);      // far segment
  depth *= 0.5f;

  atomicMin(out + pix, __float_as_int(depth));
}

// ---- fallback (ws too small): R4's proven self-contained kernel ----
__global__ __launch_bounds__(256) void depth_kernel_fb(
    const float* __restrict__ poses, const float* __restrict__ params,
    const float* __restrict__ rays_d, const float* __restrict__ rays_o,
    int* __restrict__ out)
{
  const int pix = blockIdx.x * blockDim.x + threadIdx.x;
  const int n = blockIdx.y;
  const float* P = poses + n * 16;
  const float* par = params + n * 5;
  const float is0 = 1.0f / par[0], is1 = 1.0f / par[1], is2 = 1.0f / par[2];
  const float e1 = par[3], e2 = par[4];
  const float ie1 = 1.0f / e1, ie2 = 1.0f / e2, c21 = e2 * ie1;
  const float Kq = SHARPV * e1;
  const float U = fmaxf(1.0f, __builtin_amdgcn_exp2f(1.0f - e1)) *
                  fmaxf(1.0f, __builtin_amdgcn_exp2f(1.0f - e2));
  const float thr = 1.02f * U;
  const float R00 = P[0], R01 = P[1], R02 = P[2];
  const float R10 = P[4], R11 = P[5], R12 = P[6];
  const float R20 = P[8], R21 = P[9], R22 = P[10];
  const float d0 = rays_o[0] - P[3], d1 = rays_o[1] - P[7], d2 = rays_o[2] - P[11];
  const float tc0 = (R00 * d0 + R10 * d1 + R20 * d2) * is0;
  const float tc1 = (R01 * d0 + R11 * d1 + R21 * d2) * is1;
  const float tc2 = (R02 * d0 + R12 * d1 + R22 * d2) * is2;
  const float rd0 = rays_d[pix * 3 + 0];
  const float rd1 = rays_d[pix * 3 + 1];
  const float rd2 = rays_d[pix * 3 + 2];
  const float w0 = (R00 * rd0 + R10 * rd1 + R20 * rd2) * is0;
  const float w1 = (R01 * rd0 + R11 * rd1 + R21 * rd2) * is1;
  const float w2 = (R02 * rd0 + R12 * rd1 + R22 * rd2) * is2;
  const float lam2 = w0 * w0 + w1 * w1 + w2 * w2;
  const float dd = tc0 * w0 + tc1 * w1 + tc2 * w2;
  const float pb = fabsf(dd) * __builtin_amdgcn_rcpf(lam2);
  const float ce0 = fmaf(pb, w0, tc0);
  const float ce1 = fmaf(pb, w1, tc1);
  const float ce2 = fmaf(pb, w2, tc2);
  const float dist2 = ce0 * ce0 + ce1 * ce1 + ce2 * ce2;
  if (!(dist2 < thr)) return;
  const float hb = sqrtf(fmaxf(3.0f - dist2, 1e-12f)) * rsqrtf(lam2);
  float csum = 0.0f, vp = 0.0f, depth = 0.0f, bprev = 0.0f;
#pragma unroll
  for (int k = 0; k < NSAMP + 2; k++) {
    const float b = (k == 0) ? 0.0f
                  : (k <= NSAMP) ? fmaf(fmaf((float)(k - 1), DT9, -1.0f), hb, pb)
                  : FARV;
    const float lf = lf_eval(fmaf(b, w0, tc0), fmaf(b, w1, tc1), fmaf(b, w2, tc2),
                             ie1, ie2, c21);
    csum += __builtin_amdgcn_rcpf(1.0f + __builtin_amdgcn_exp2f(Kq * lf));
    const float vis = __builtin_amdgcn_exp2f(-TAU2 * csum);
    if (k) depth += 0.5f * (vp + vis) * fabsf(b - bprev);
    vp = vis; bprev = b;
  }
  atomicMin(out + pix, __float_as_int(depth));
}

__global__ __launch_bounds__(256) void fill_only(float* __restrict__ out) {
  out[blockIdx.x * blockDim.x + threadIdx.x] = FARV;
}

extern "C" void kernel_launch(void* const* d_in, const int* in_sizes, int n_in,
                              void* d_out, int out_size, void* d_ws, size_t ws_size,
                              hipStream_t stream) {
  const float* poses  = (const float*)d_in[0];
  const float* params = (const float*)d_in[1];
  const float* rays_d = (const float*)d_in[2];
  const float* rays_o = (const float*)d_in[3];

  const int block = 256;
  const int gridx = NPIX / block;   // 900, exact

  if (ws_size >= NSQ * TSTRIDE * sizeof(float)) {
    float* tab = (float*)d_ws;
    fill_kernel<<<gridx, block, 0, stream>>>((float*)d_out, poses, params, rays_o, tab);
    depth_kernel<<<dim3(gridx, NSQ), block, 0, stream>>>(rays_d, tab, (int*)d_out);
  } else {
    fill_only<<<gridx, block, 0, stream>>>((float*)d_out);
    depth_kernel_fb<<<dim3(gridx, NSQ), block, 0, stream>>>(
        poses, params, rays_d, rays_o, (int*)d_out);
  }
}

// Round 7
// 13.265 us; speedup vs baseline: 2.1064x; 1.2661x over previous
//
#include <hip/hip_runtime.h>

constexpr int NPIX = 360 * 640;            // 230400 = 900 * 256 exactly
constexpr int NSQ = 8, NSAMP = 10;
constexpr float FARV = 1.5f;
constexpr float SHARPV = 1000.0f;
constexpr float TAU2 = 100.0f * 1.44269504f;   // TAU * log2(e)
constexpr float DT9 = 2.0f / 9.0f;

struct SQT {
  float A[9];      // R * diag(1/s):  w_j = sum_i A[i][j] * rd_i
  float tc[3];
  float ie1, ie2, c21, Kq;
  float thr;       // 1.02 * exact circumscribed radius^2
  float vis0;      // vis at near point (beta=0, pixel-independent)
};

// log2 f, f = (y0^(1/e2)+y1^(1/e2))^(e2/e1) + y2^(1/e1), y = q^2+1e-12
__device__ __forceinline__ float lf_eval(float q0, float q1, float q2,
                                         float ie1, float ie2, float c21) {
  const float y0 = fmaf(q0, q0, 1e-12f);
  const float y1 = fmaf(q1, q1, 1e-12f);
  const float y2 = fmaf(q2, q2, 1e-12f);
  const float la = ie2 * __builtin_amdgcn_logf(y0);
  const float lb = ie2 * __builtin_amdgcn_logf(y1);
  const float lc = ie1 * __builtin_amdgcn_logf(y2);
  const float mab = fmaxf(la, lb), nab = fminf(la, lb);
  const float lab = mab + __builtin_amdgcn_logf(1.0f + __builtin_amdgcn_exp2f(nab - mab));
  const float lg = c21 * lab;
  const float mf = fmaxf(lg, lc), nf = fminf(lg, lc);
  return mf + __builtin_amdgcn_logf(1.0f + __builtin_amdgcn_exp2f(nf - mf));
}

__global__ __launch_bounds__(256) void depth_kernel(
    const float* __restrict__ poses, const float* __restrict__ params,
    const float* __restrict__ rays_d, const float* __restrict__ rays_o,
    float* __restrict__ out)
{
  __shared__ SQT sq[NSQ];
  const int tid = threadIdx.x;

  if (tid < NSQ) {
    const int n = tid;
    const float* P = poses + n * 16;
    const float* par = params + n * 5;
    const float is0 = 1.0f / par[0], is1 = 1.0f / par[1], is2 = 1.0f / par[2];
    const float e1 = par[3], e2 = par[4];
    SQT q;
    q.A[0] = P[0] * is0;  q.A[1] = P[1] * is1;  q.A[2] = P[2]  * is2;
    q.A[3] = P[4] * is0;  q.A[4] = P[5] * is1;  q.A[5] = P[6]  * is2;
    q.A[6] = P[8] * is0;  q.A[7] = P[9] * is1;  q.A[8] = P[10] * is2;
    const float d0 = rays_o[0] - P[3], d1 = rays_o[1] - P[7], d2 = rays_o[2] - P[11];
    q.tc[0] = q.A[0] * d0 + q.A[3] * d1 + q.A[6] * d2;
    q.tc[1] = q.A[1] * d0 + q.A[4] * d1 + q.A[7] * d2;
    q.tc[2] = q.A[2] * d0 + q.A[5] * d1 + q.A[8] * d2;
    q.ie1 = 1.0f / e1; q.ie2 = 1.0f / e2; q.c21 = e2 * q.ie1;
    q.Kq = SHARPV * e1;
    // exact circumscribed radius^2 of F=1 surface (squared-coord frame)
    const float c = __builtin_amdgcn_exp2f(1.0f - e2);
    const float V1 = (e1 < 1.0f) ? __builtin_amdgcn_exp2f(1.0f - e1) : 1.0f;
    float V2;
    if (e1 < 0.999f) {
      const float cp = __builtin_amdgcn_exp2f((1.0f - e2) / (1.0f - e1));
      V2 = __builtin_amdgcn_exp2f((1.0f - e1) * __builtin_amdgcn_logf(1.0f + cp));
    } else {
      V2 = fmaxf(c, 1.0f);
    }
    q.thr = 1.02f * fmaxf(V1, V2);
    const float lf0 = lf_eval(q.tc[0], q.tc[1], q.tc[2], q.ie1, q.ie2, q.c21);
    const float occ0 = __builtin_amdgcn_rcpf(1.0f + __builtin_amdgcn_exp2f(q.Kq * lf0));
    q.vis0 = __builtin_amdgcn_exp2f(-TAU2 * occ0);
    sq[n] = q;
  }
  __syncthreads();

  const int pix = blockIdx.x * blockDim.x + tid;
  const float rd0 = rays_d[pix * 3 + 0];
  const float rd1 = rays_d[pix * 3 + 1];
  const float rd2 = rays_d[pix * 3 + 2];

  float m = FARV;

  for (int n = 0; n < NSQ; n++) {
    const SQT& q = sq[n];   // broadcast LDS reads (conflict-free)
    const float w0 = q.A[0] * rd0 + q.A[3] * rd1 + q.A[6] * rd2;
    const float w1 = q.A[1] * rd0 + q.A[4] * rd1 + q.A[7] * rd2;
    const float w2 = q.A[2] * rd0 + q.A[5] * rd1 + q.A[8] * rd2;
    const float tc0 = q.tc[0], tc1 = q.tc[1], tc2 = q.tc[2];

    const float lam2 = w0 * w0 + w1 * w1 + w2 * w2;
    const float dd = tc0 * w0 + tc1 * w1 + tc2 * w2;
    const float pb = fabsf(dd) * __builtin_amdgcn_rcpf(lam2);  // closest approach
    const float ce0 = fmaf(pb, w0, tc0);
    const float ce1 = fmaf(pb, w1, tc1);
    const float ce2 = fmaf(pb, w2, tc2);
    const float dist2 = ce0 * ce0 + ce1 * ce1 + ce2 * ce2;
    const bool hit = dist2 < q.thr;
    if (!__any(hit)) continue;          // wave-uniform skip

    const float hb = sqrtf(fmaxf(3.0f - dist2, 1e-12f)) * rsqrtf(lam2);
    const float ie1 = q.ie1, ie2 = q.ie2, c21 = q.c21, Kq = q.Kq;

    float ev[NSAMP + 1];
#pragma unroll
    for (int k = 0; k <= NSAMP; k++) {
      const float b = (k < NSAMP) ? fmaf(fmaf((float)k, DT9, -1.0f), hb, pb) : FARV;
      const float lf = lf_eval(fmaf(b, w0, tc0), fmaf(b, w1, tc1), fmaf(b, w2, tc2),
                               ie1, ie2, c21);
      const float occ = __builtin_amdgcn_rcpf(1.0f + __builtin_amdgcn_exp2f(Kq * lf));
      ev[k] = __builtin_amdgcn_exp2f(-TAU2 * occ);
    }

    float v = q.vis0;
    float vn = v * ev[0];
    float depth = (v + vn) * fabsf(pb - hb);      // near segment
    v = vn;
    float mid = 0.0f;
#pragma unroll
    for (int k = 1; k < NSAMP; k++) { vn = v * ev[k]; mid += v + vn; v = vn; }
    depth += mid * (hb * DT9);                     // uniform interior spacing
    vn = v * ev[NSAMP];
    depth += (v + vn) * fabsf(FARV - pb - hb);     // far segment
    depth *= 0.5f;

    m = fminf(m, hit ? depth : FARV);
  }

  out[pix] = m;
}

extern "C" void kernel_launch(void* const* d_in, const int* in_sizes, int n_in,
                              void* d_out, int out_size, void* d_ws, size_t ws_size,
                              hipStream_t stream) {
  const float* poses  = (const float*)d_in[0];
  const float* params = (const float*)d_in[1];
  const float* rays_d = (const float*)d_in[2];
  const float* rays_o = (const float*)d_in[3];

  depth_kernel<<<NPIX / 256, 256, 0, stream>>>(
      poses, params, rays_d, rays_o, (float*)d_out);
}